// Round 2
// baseline (681.264 us; speedup 1.0000x reference)
//
#include <hip/hip_runtime.h>
#include <math.h>

// softIoULoss: out = 1 - (I + 1) / (M + (nc+1)*S - I + 1)
//   I = sum(sigmoid(0.5 - |x-t|) * matched)
//   M = sum(matched),  S = sum(sigmoid(0.5 - |x-t|))
//   matched = (t == floor(t)) && (t >= 0) && (t <= nc)
//
// R1 analysis: VGPR=16 kernel was latency-bound (1.37 TB/s effective, VALUBusy 8%).
// R2: 8 independent dwordx4 loads issued back-to-back per iteration -> 8x MLP.
// Grid sized so N=2^25 is exactly one macro-iteration per thread (no carried dep).
//
// ws layout: [0..2] float accumulators (I, M, S), [3] uint32 block counter.

__device__ __forceinline__ void accum4(float4 xv, float4 tv, float ncf,
                                       float& s_inter, float& s_match, float& s_sig) {
    float xs[4] = {xv.x, xv.y, xv.z, xv.w};
    float ts[4] = {tv.x, tv.y, tv.z, tv.w};
#pragma unroll
    for (int j = 0; j < 4; ++j) {
        float tt = ts[j];
        float z  = 0.5f - fabsf(xs[j] - tt);
        float sg = __builtin_amdgcn_rcpf(1.0f + __expf(-z));
        float m  = (tt == floorf(tt) && tt >= 0.f && tt <= ncf) ? 1.f : 0.f;
        s_sig   += sg;
        s_match += m;
        s_inter += sg * m;
    }
}

__global__ __launch_bounds__(256) void soft_iou_kernel(
    const float* __restrict__ x,
    const float* __restrict__ t,
    const int* __restrict__ ncls_p,
    float* __restrict__ out,
    float* __restrict__ ws_f,
    unsigned int* __restrict__ ws_cnt,
    int n)
{
    const int tid = threadIdx.x;
    const long long nthreads = (long long)gridDim.x * blockDim.x;
    const long long gtid     = (long long)blockIdx.x * blockDim.x + tid;

    const float ncf = (float)(*ncls_p);

    float s_inter = 0.f, s_match = 0.f, s_sig = 0.f;

    const long long nvec = (long long)n >> 2;   // float4 count
    const float4* __restrict__ x4 = (const float4*)x;
    const float4* __restrict__ t4 = (const float4*)t;

    long long i = gtid;
    // macro iteration: 4 coalesced float4 loads per array, all independent,
    // issued before any consumption -> 8 KB/wave in flight.
    for (; i + 3 * nthreads < nvec; i += 4 * nthreads) {
        float4 xv0 = x4[i];
        float4 xv1 = x4[i +     nthreads];
        float4 xv2 = x4[i + 2 * nthreads];
        float4 xv3 = x4[i + 3 * nthreads];
        float4 tv0 = t4[i];
        float4 tv1 = t4[i +     nthreads];
        float4 tv2 = t4[i + 2 * nthreads];
        float4 tv3 = t4[i + 3 * nthreads];
        accum4(xv0, tv0, ncf, s_inter, s_match, s_sig);
        accum4(xv1, tv1, ncf, s_inter, s_match, s_sig);
        accum4(xv2, tv2, ncf, s_inter, s_match, s_sig);
        accum4(xv3, tv3, ncf, s_inter, s_match, s_sig);
    }
    // remaining full float4s
    for (; i < nvec; i += nthreads) {
        accum4(x4[i], t4[i], ncf, s_inter, s_match, s_sig);
    }
    // scalar tail (n % 4)
    for (long long k = (nvec << 2) + gtid; k < n; k += nthreads) {
        float tt = t[k];
        float z  = 0.5f - fabsf(x[k] - tt);
        float sg = __builtin_amdgcn_rcpf(1.0f + __expf(-z));
        float m  = (tt == floorf(tt) && tt >= 0.f && tt <= ncf) ? 1.f : 0.f;
        s_sig += sg; s_match += m; s_inter += sg * m;
    }

    // wave (64-lane) reduction
#pragma unroll
    for (int off = 32; off > 0; off >>= 1) {
        s_inter += __shfl_down(s_inter, off, 64);
        s_match += __shfl_down(s_match, off, 64);
        s_sig   += __shfl_down(s_sig,   off, 64);
    }

    __shared__ float sh[3][4];   // 4 waves for block=256
    const int wid = tid >> 6;
    const int lid = tid & 63;
    if (lid == 0) { sh[0][wid] = s_inter; sh[1][wid] = s_match; sh[2][wid] = s_sig; }
    __syncthreads();

    if (tid == 0) {
        float bi = sh[0][0] + sh[0][1] + sh[0][2] + sh[0][3];
        float bm = sh[1][0] + sh[1][1] + sh[1][2] + sh[1][3];
        float bs = sh[2][0] + sh[2][1] + sh[2][2] + sh[2][3];
        atomicAdd(&ws_f[0], bi);
        atomicAdd(&ws_f[1], bm);
        atomicAdd(&ws_f[2], bs);
        __threadfence();
        unsigned prev = atomicAdd(ws_cnt, 1u);
        if (prev == gridDim.x - 1) {
            // last block: all adds globally visible; read via atomic RMW (+0)
            // to bypass stale per-XCD caches.
            float I = atomicAdd(&ws_f[0], 0.f);
            float M = atomicAdd(&ws_f[1], 0.f);
            float S = atomicAdd(&ws_f[2], 0.f);
            float uni = M + (ncf + 1.f) * S - I;
            out[0] = 1.f - (I + 1.f) / (uni + 1.f);
        }
    }
}

extern "C" void kernel_launch(void* const* d_in, const int* in_sizes, int n_in,
                              void* d_out, int out_size, void* d_ws, size_t ws_size,
                              hipStream_t stream) {
    const float* x  = (const float*)d_in[0];
    const float* t  = (const float*)d_in[1];
    const int*   nc = (const int*)d_in[2];
    float* out = (float*)d_out;
    float* ws_f = (float*)d_ws;
    unsigned int* ws_cnt = (unsigned int*)((char*)d_ws + 12);
    const int n = in_sizes[0];

    hipMemsetAsync(d_ws, 0, 16, stream);

    const int block = 256;
    // one macro-iteration (16 elements) per thread: grid = ceil(n/16/256)
    long long nvec = (long long)n >> 2;
    long long threads_needed = (nvec + 3) / 4;
    int grid = (int)((threads_needed + block - 1) / block);
    if (grid < 1) grid = 1;
    if (grid > 16384) grid = 16384;   // safety cap; grid-stride loop covers rest
    soft_iou_kernel<<<grid, block, 0, stream>>>(x, t, nc, out, ws_f, ws_cnt, n);
}

// Round 3
// 280.307 us; speedup vs baseline: 2.4304x; 2.4304x over previous
//
#include <hip/hip_runtime.h>
#include <math.h>

// softIoULoss: out = 1 - (I + 1) / (M + (nc+1)*S - I + 1)
//   I = sum(sigmoid(0.5 - |x-t|) * matched)
//   M = sum(matched),  S = sum(sigmoid(0.5 - |x-t|))
//   matched = (t == floor(t)) && (t >= 0) && (t <= nc)
//
// R2 post-mortem: same-address atomicAdd serialization dominated (505 us with
// reads fully L3-cached; WRITE_SIZE scaled with grid). R3: atomic-free.
// Kernel 1 writes per-block partials to distinct ws slots; kernel 2 (1 block)
// reduces them. No memset needed (all ws slots written unconditionally).

#define GRID1 2048

__device__ __forceinline__ void accum4(float4 xv, float4 tv, float ncf,
                                       float& s_inter, float& s_match, float& s_sig) {
    float xs[4] = {xv.x, xv.y, xv.z, xv.w};
    float ts[4] = {tv.x, tv.y, tv.z, tv.w};
#pragma unroll
    for (int j = 0; j < 4; ++j) {
        float tt = ts[j];
        float z  = 0.5f - fabsf(xs[j] - tt);
        float sg = __builtin_amdgcn_rcpf(1.0f + __expf(-z));
        float m  = (tt == floorf(tt) && tt >= 0.f && tt <= ncf) ? 1.f : 0.f;
        s_sig   += sg;
        s_match += m;
        s_inter += sg * m;
    }
}

__global__ __launch_bounds__(256) void soft_iou_partial(
    const float* __restrict__ x,
    const float* __restrict__ t,
    const int* __restrict__ ncls_p,
    float* __restrict__ pI,     // [gridDim.x]
    float* __restrict__ pM,     // [gridDim.x]
    float* __restrict__ pS,     // [gridDim.x]
    int n)
{
    const int tid = threadIdx.x;
    const long long nthreads = (long long)gridDim.x * blockDim.x;
    const long long gtid     = (long long)blockIdx.x * blockDim.x + tid;

    const float ncf = (float)(*ncls_p);

    float s_inter = 0.f, s_match = 0.f, s_sig = 0.f;

    const long long nvec = (long long)n >> 2;   // float4 count
    const float4* __restrict__ x4 = (const float4*)x;
    const float4* __restrict__ t4 = (const float4*)t;

    long long i = gtid;
    // macro iteration: 4 independent coalesced float4 loads per array issued
    // before any consumption -> 8 dwordx4 in flight per thread.
    for (; i + 3 * nthreads < nvec; i += 4 * nthreads) {
        float4 xv0 = x4[i];
        float4 xv1 = x4[i +     nthreads];
        float4 xv2 = x4[i + 2 * nthreads];
        float4 xv3 = x4[i + 3 * nthreads];
        float4 tv0 = t4[i];
        float4 tv1 = t4[i +     nthreads];
        float4 tv2 = t4[i + 2 * nthreads];
        float4 tv3 = t4[i + 3 * nthreads];
        accum4(xv0, tv0, ncf, s_inter, s_match, s_sig);
        accum4(xv1, tv1, ncf, s_inter, s_match, s_sig);
        accum4(xv2, tv2, ncf, s_inter, s_match, s_sig);
        accum4(xv3, tv3, ncf, s_inter, s_match, s_sig);
    }
    for (; i < nvec; i += nthreads) {
        accum4(x4[i], t4[i], ncf, s_inter, s_match, s_sig);
    }
    // scalar tail (n % 4)
    for (long long k = (nvec << 2) + gtid; k < n; k += nthreads) {
        float tt = t[k];
        float z  = 0.5f - fabsf(x[k] - tt);
        float sg = __builtin_amdgcn_rcpf(1.0f + __expf(-z));
        float m  = (tt == floorf(tt) && tt >= 0.f && tt <= ncf) ? 1.f : 0.f;
        s_sig += sg; s_match += m; s_inter += sg * m;
    }

    // wave (64-lane) reduction
#pragma unroll
    for (int off = 32; off > 0; off >>= 1) {
        s_inter += __shfl_down(s_inter, off, 64);
        s_match += __shfl_down(s_match, off, 64);
        s_sig   += __shfl_down(s_sig,   off, 64);
    }

    __shared__ float sh[3][4];   // 4 waves for block=256
    const int wid = tid >> 6;
    const int lid = tid & 63;
    if (lid == 0) { sh[0][wid] = s_inter; sh[1][wid] = s_match; sh[2][wid] = s_sig; }
    __syncthreads();

    if (tid == 0) {
        pI[blockIdx.x] = sh[0][0] + sh[0][1] + sh[0][2] + sh[0][3];
        pM[blockIdx.x] = sh[1][0] + sh[1][1] + sh[1][2] + sh[1][3];
        pS[blockIdx.x] = sh[2][0] + sh[2][1] + sh[2][2] + sh[2][3];
    }
}

__global__ __launch_bounds__(256) void soft_iou_final(
    const float* __restrict__ pI,
    const float* __restrict__ pM,
    const float* __restrict__ pS,
    const int* __restrict__ ncls_p,
    float* __restrict__ out,
    int g)
{
    const int tid = threadIdx.x;
    float si = 0.f, sm = 0.f, ss = 0.f;
    for (int i = tid; i < g; i += 256) {
        si += pI[i];
        sm += pM[i];
        ss += pS[i];
    }
#pragma unroll
    for (int off = 32; off > 0; off >>= 1) {
        si += __shfl_down(si, off, 64);
        sm += __shfl_down(sm, off, 64);
        ss += __shfl_down(ss, off, 64);
    }
    __shared__ float sh[3][4];
    const int wid = tid >> 6;
    const int lid = tid & 63;
    if (lid == 0) { sh[0][wid] = si; sh[1][wid] = sm; sh[2][wid] = ss; }
    __syncthreads();
    if (tid == 0) {
        float I = sh[0][0] + sh[0][1] + sh[0][2] + sh[0][3];
        float M = sh[1][0] + sh[1][1] + sh[1][2] + sh[1][3];
        float S = sh[2][0] + sh[2][1] + sh[2][2] + sh[2][3];
        float ncf = (float)(*ncls_p);
        float uni = M + (ncf + 1.f) * S - I;
        out[0] = 1.f - (I + 1.f) / (uni + 1.f);
    }
}

extern "C" void kernel_launch(void* const* d_in, const int* in_sizes, int n_in,
                              void* d_out, int out_size, void* d_ws, size_t ws_size,
                              hipStream_t stream) {
    const float* x  = (const float*)d_in[0];
    const float* t  = (const float*)d_in[1];
    const int*   nc = (const int*)d_in[2];
    float* out = (float*)d_out;
    const int n = in_sizes[0];

    float* pI = (float*)d_ws;
    float* pM = pI + GRID1;
    float* pS = pM + GRID1;

    soft_iou_partial<<<GRID1, 256, 0, stream>>>(x, t, nc, pI, pM, pS, n);
    soft_iou_final<<<1, 256, 0, stream>>>(pI, pM, pS, nc, out, GRID1);
}

// Round 5
// 272.154 us; speedup vs baseline: 2.5032x; 1.0300x over previous
//
#include <hip/hip_runtime.h>
#include <math.h>

// softIoULoss: out = 1 - (I + 1) / (M + (nc+1)*S - I + 1)
//   I = sum(sigmoid(0.5 - |x-t|) * matched)
//   M = sum(matched),  S = sum(sigmoid(0.5 - |x-t|))
//   matched = (t == floor(t)) && (t >= 0) && (t <= nc)
//
// R3 post-mortem: kernel 112 us with L3-hot inputs, VALUBusy 8% -> 90% memory
// stall. VGPR=36 shows compiler de-pipelined the 8-load batch (MLP~2).
// R4/R5: straight-line round of 16 NT loads into a register array,
// sched_barrier(0) to pin all loads before compute; clang-native float4
// (ext_vector_type) because __builtin_nontemporal_load rejects HIP_vector_type.
// Atomic-free two-kernel reduction as in R3.

#define BLOCK 256
#define PAIRS 8    // float4-pairs per thread per straight-line round
#define MAXGRID 16384

typedef float f4_t __attribute__((ext_vector_type(4)));

__device__ __forceinline__ void accum4(f4_t xv, f4_t tv, float ncf,
                                       float& s_inter, float& s_match, float& s_sig) {
#pragma unroll
    for (int j = 0; j < 4; ++j) {
        float tt = tv[j];
        float z  = 0.5f - fabsf(xv[j] - tt);
        float sg = __builtin_amdgcn_rcpf(1.0f + __expf(-z));
        float m  = (tt == floorf(tt) && tt >= 0.f && tt <= ncf) ? 1.f : 0.f;
        s_sig   += sg;
        s_match += m;
        s_inter += sg * m;
    }
}

__global__ __launch_bounds__(BLOCK) void soft_iou_partial(
    const float* __restrict__ x,
    const float* __restrict__ t,
    const int* __restrict__ ncls_p,
    float* __restrict__ pI,     // [gridDim.x]
    float* __restrict__ pM,     // [gridDim.x]
    float* __restrict__ pS,     // [gridDim.x]
    int n)
{
    const int tid = threadIdx.x;
    const long long nthreads = (long long)gridDim.x * BLOCK;
    const long long gtid     = (long long)blockIdx.x * BLOCK + tid;

    const float ncf = (float)(*ncls_p);

    float s_inter = 0.f, s_match = 0.f, s_sig = 0.f;

    const long long nvec = (long long)n >> 2;   // float4 count
    const f4_t* __restrict__ x4 = (const f4_t*)x;
    const f4_t* __restrict__ t4 = (const f4_t*)t;

    long long i = gtid;
    // straight-line round: 16 independent nontemporal dwordx4 loads into a
    // register array, sched_barrier pins them all before any consumption.
    for (; i + (PAIRS - 1) * nthreads < nvec; i += (long long)PAIRS * nthreads) {
        f4_t xv[PAIRS], tv[PAIRS];
#pragma unroll
        for (int k = 0; k < PAIRS; ++k)
            xv[k] = __builtin_nontemporal_load(&x4[i + (long long)k * nthreads]);
#pragma unroll
        for (int k = 0; k < PAIRS; ++k)
            tv[k] = __builtin_nontemporal_load(&t4[i + (long long)k * nthreads]);
        __builtin_amdgcn_sched_barrier(0);
#pragma unroll
        for (int k = 0; k < PAIRS; ++k)
            accum4(xv[k], tv[k], ncf, s_inter, s_match, s_sig);
    }
    // remaining full float4s
    for (; i < nvec; i += nthreads) {
        accum4(x4[i], t4[i], ncf, s_inter, s_match, s_sig);
    }
    // scalar tail (n % 4)
    for (long long k = (nvec << 2) + gtid; k < n; k += nthreads) {
        float tt = t[k];
        float z  = 0.5f - fabsf(x[k] - tt);
        float sg = __builtin_amdgcn_rcpf(1.0f + __expf(-z));
        float m  = (tt == floorf(tt) && tt >= 0.f && tt <= ncf) ? 1.f : 0.f;
        s_sig += sg; s_match += m; s_inter += sg * m;
    }

    // wave (64-lane) reduction
#pragma unroll
    for (int off = 32; off > 0; off >>= 1) {
        s_inter += __shfl_down(s_inter, off, 64);
        s_match += __shfl_down(s_match, off, 64);
        s_sig   += __shfl_down(s_sig,   off, 64);
    }

    __shared__ float sh[3][4];   // 4 waves for block=256
    const int wid = tid >> 6;
    const int lid = tid & 63;
    if (lid == 0) { sh[0][wid] = s_inter; sh[1][wid] = s_match; sh[2][wid] = s_sig; }
    __syncthreads();

    if (tid == 0) {
        pI[blockIdx.x] = sh[0][0] + sh[0][1] + sh[0][2] + sh[0][3];
        pM[blockIdx.x] = sh[1][0] + sh[1][1] + sh[1][2] + sh[1][3];
        pS[blockIdx.x] = sh[2][0] + sh[2][1] + sh[2][2] + sh[2][3];
    }
}

__global__ __launch_bounds__(256) void soft_iou_final(
    const float* __restrict__ pI,
    const float* __restrict__ pM,
    const float* __restrict__ pS,
    const int* __restrict__ ncls_p,
    float* __restrict__ out,
    int g)
{
    const int tid = threadIdx.x;
    float si = 0.f, sm = 0.f, ss = 0.f;
    for (int i = tid; i < g; i += 256) {
        si += pI[i];
        sm += pM[i];
        ss += pS[i];
    }
#pragma unroll
    for (int off = 32; off > 0; off >>= 1) {
        si += __shfl_down(si, off, 64);
        sm += __shfl_down(sm, off, 64);
        ss += __shfl_down(ss, off, 64);
    }
    __shared__ float sh[3][4];
    const int wid = tid >> 6;
    const int lid = tid & 63;
    if (lid == 0) { sh[0][wid] = si; sh[1][wid] = sm; sh[2][wid] = ss; }
    __syncthreads();
    if (tid == 0) {
        float I = sh[0][0] + sh[0][1] + sh[0][2] + sh[0][3];
        float M = sh[1][0] + sh[1][1] + sh[1][2] + sh[1][3];
        float S = sh[2][0] + sh[2][1] + sh[2][2] + sh[2][3];
        float ncf = (float)(*ncls_p);
        float uni = M + (ncf + 1.f) * S - I;
        out[0] = 1.f - (I + 1.f) / (uni + 1.f);
    }
}

extern "C" void kernel_launch(void* const* d_in, const int* in_sizes, int n_in,
                              void* d_out, int out_size, void* d_ws, size_t ws_size,
                              hipStream_t stream) {
    const float* x  = (const float*)d_in[0];
    const float* t  = (const float*)d_in[1];
    const int*   nc = (const int*)d_in[2];
    float* out = (float*)d_out;
    const int n = in_sizes[0];

    // grid sized so most threads do exactly one straight-line round
    long long nvec = (long long)n >> 2;
    long long threads_needed = (nvec + PAIRS - 1) / PAIRS;
    int grid = (int)((threads_needed + BLOCK - 1) / BLOCK);
    if (grid < 1) grid = 1;
    if (grid > MAXGRID) grid = MAXGRID;

    float* pI = (float*)d_ws;
    float* pM = pI + MAXGRID;
    float* pS = pM + MAXGRID;

    soft_iou_partial<<<grid, BLOCK, 0, stream>>>(x, t, nc, pI, pM, pS, n);
    soft_iou_final<<<1, 256, 0, stream>>>(pI, pM, pS, nc, out, grid);
}

// Round 6
// 263.947 us; speedup vs baseline: 2.5811x; 1.0311x over previous
//
#include <hip/hip_runtime.h>
#include <math.h>

// softIoULoss: out = 1 - (I + 1) / (M + (nc+1)*S - I + 1)
//   I = sum(sigmoid(0.5 - |x-t|) * matched)
//   M = sum(matched),  S = sum(sigmoid(0.5 - |x-t|))
//   matched = (t == floor(t)) && (t >= 0) && (t <= nc)
//
// R5 post-mortem: kernel now <=77 us (out of top-5; harness fills dominate).
// R6: interleave x/t load issue (first accum waits vmcnt(14) not vmcnt(7)),
// PAIRS=4 + grid 8192 (lower VGPR, 2x wave occupancy, finer load balance).
// Harness's 512MB ws poison evicts L3 each iter -> reads are HBM-sourced;
// floor = 268 MB / 6.3 TB/s ~= 43 us.

#define BLOCK 256
#define PAIRS 4    // float4-pairs per thread per straight-line round
#define MAXGRID 16384

typedef float f4_t __attribute__((ext_vector_type(4)));

__device__ __forceinline__ void accum4(f4_t xv, f4_t tv, float ncf,
                                       float& s_inter, float& s_match, float& s_sig) {
#pragma unroll
    for (int j = 0; j < 4; ++j) {
        float tt = tv[j];
        float z  = 0.5f - fabsf(xv[j] - tt);
        float sg = __builtin_amdgcn_rcpf(1.0f + __expf(-z));
        float m  = (tt == floorf(tt) && tt >= 0.f && tt <= ncf) ? 1.f : 0.f;
        s_sig   += sg;
        s_match += m;
        s_inter += sg * m;
    }
}

__global__ __launch_bounds__(BLOCK) void soft_iou_partial(
    const float* __restrict__ x,
    const float* __restrict__ t,
    const int* __restrict__ ncls_p,
    float* __restrict__ pI,     // [gridDim.x]
    float* __restrict__ pM,     // [gridDim.x]
    float* __restrict__ pS,     // [gridDim.x]
    int n)
{
    const int tid = threadIdx.x;
    const long long nthreads = (long long)gridDim.x * BLOCK;
    const long long gtid     = (long long)blockIdx.x * BLOCK + tid;

    const float ncf = (float)(*ncls_p);

    float s_inter = 0.f, s_match = 0.f, s_sig = 0.f;

    const long long nvec = (long long)n >> 2;   // float4 count
    const f4_t* __restrict__ x4 = (const f4_t*)x;
    const f4_t* __restrict__ t4 = (const f4_t*)t;

    long long i = gtid;
    // straight-line round: 2*PAIRS independent NT dwordx4 loads, interleaved
    // x/t so the k-th accum only needs the two oldest outstanding loads.
    for (; i + (PAIRS - 1) * nthreads < nvec; i += (long long)PAIRS * nthreads) {
        f4_t xv[PAIRS], tv[PAIRS];
#pragma unroll
        for (int k = 0; k < PAIRS; ++k) {
            xv[k] = __builtin_nontemporal_load(&x4[i + (long long)k * nthreads]);
            tv[k] = __builtin_nontemporal_load(&t4[i + (long long)k * nthreads]);
        }
        __builtin_amdgcn_sched_barrier(0);
#pragma unroll
        for (int k = 0; k < PAIRS; ++k)
            accum4(xv[k], tv[k], ncf, s_inter, s_match, s_sig);
    }
    // remaining full float4s
    for (; i < nvec; i += nthreads) {
        accum4(x4[i], t4[i], ncf, s_inter, s_match, s_sig);
    }
    // scalar tail (n % 4)
    for (long long k = (nvec << 2) + gtid; k < n; k += nthreads) {
        float tt = t[k];
        float z  = 0.5f - fabsf(x[k] - tt);
        float sg = __builtin_amdgcn_rcpf(1.0f + __expf(-z));
        float m  = (tt == floorf(tt) && tt >= 0.f && tt <= ncf) ? 1.f : 0.f;
        s_sig += sg; s_match += m; s_inter += sg * m;
    }

    // wave (64-lane) reduction
#pragma unroll
    for (int off = 32; off > 0; off >>= 1) {
        s_inter += __shfl_down(s_inter, off, 64);
        s_match += __shfl_down(s_match, off, 64);
        s_sig   += __shfl_down(s_sig,   off, 64);
    }

    __shared__ float sh[3][4];   // 4 waves for block=256
    const int wid = tid >> 6;
    const int lid = tid & 63;
    if (lid == 0) { sh[0][wid] = s_inter; sh[1][wid] = s_match; sh[2][wid] = s_sig; }
    __syncthreads();

    if (tid == 0) {
        pI[blockIdx.x] = sh[0][0] + sh[0][1] + sh[0][2] + sh[0][3];
        pM[blockIdx.x] = sh[1][0] + sh[1][1] + sh[1][2] + sh[1][3];
        pS[blockIdx.x] = sh[2][0] + sh[2][1] + sh[2][2] + sh[2][3];
    }
}

__global__ __launch_bounds__(256) void soft_iou_final(
    const float* __restrict__ pI,
    const float* __restrict__ pM,
    const float* __restrict__ pS,
    const int* __restrict__ ncls_p,
    float* __restrict__ out,
    int g)
{
    const int tid = threadIdx.x;
    float si = 0.f, sm = 0.f, ss = 0.f;
    for (int i = tid; i < g; i += 256) {
        si += pI[i];
        sm += pM[i];
        ss += pS[i];
    }
#pragma unroll
    for (int off = 32; off > 0; off >>= 1) {
        si += __shfl_down(si, off, 64);
        sm += __shfl_down(sm, off, 64);
        ss += __shfl_down(ss, off, 64);
    }
    __shared__ float sh[3][4];
    const int wid = tid >> 6;
    const int lid = tid & 63;
    if (lid == 0) { sh[0][wid] = si; sh[1][wid] = sm; sh[2][wid] = ss; }
    __syncthreads();
    if (tid == 0) {
        float I = sh[0][0] + sh[0][1] + sh[0][2] + sh[0][3];
        float M = sh[1][0] + sh[1][1] + sh[1][2] + sh[1][3];
        float S = sh[2][0] + sh[2][1] + sh[2][2] + sh[2][3];
        float ncf = (float)(*ncls_p);
        float uni = M + (ncf + 1.f) * S - I;
        out[0] = 1.f - (I + 1.f) / (uni + 1.f);
    }
}

extern "C" void kernel_launch(void* const* d_in, const int* in_sizes, int n_in,
                              void* d_out, int out_size, void* d_ws, size_t ws_size,
                              hipStream_t stream) {
    const float* x  = (const float*)d_in[0];
    const float* t  = (const float*)d_in[1];
    const int*   nc = (const int*)d_in[2];
    float* out = (float*)d_out;
    const int n = in_sizes[0];

    // grid sized so most threads do exactly one straight-line round
    long long nvec = (long long)n >> 2;
    long long threads_needed = (nvec + PAIRS - 1) / PAIRS;
    int grid = (int)((threads_needed + BLOCK - 1) / BLOCK);
    if (grid < 1) grid = 1;
    if (grid > MAXGRID) grid = MAXGRID;

    float* pI = (float*)d_ws;
    float* pM = pI + MAXGRID;
    float* pS = pM + MAXGRID;

    soft_iou_partial<<<grid, BLOCK, 0, stream>>>(x, t, nc, pI, pM, pS, n);
    soft_iou_final<<<1, 256, 0, stream>>>(pI, pM, pS, nc, out, grid);
}

// Round 7
// 257.242 us; speedup vs baseline: 2.6483x; 1.0261x over previous
//
#include <hip/hip_runtime.h>
#include <math.h>

// softIoULoss: out = 1 - (I + 1) / (M + (nc+1)*S - I + 1)
//   I = sum(sigmoid(0.5 - |x-t|) * matched)
//   M = sum(matched),  S = sum(sigmoid(0.5 - |x-t|))
//   matched = (t == floor(t)) && (t >= 0) && (t <= nc)
//
// R6 post-mortem: kernel below top-5 (<77 us, floor 43 us); bench 264 with
// ~160-190 us fixed harness reset. R7: PAIRS=8 WITH x/t interleave (R6 gain
// conflated interleave with depth change) -> 16 loads in flight/thread;
// vectorized finalize. If neutral, we're at the HBM floor.

#define BLOCK 256
#define PAIRS 8    // float4-pairs per thread per straight-line round
#define MAXGRID 16384

typedef float f4_t __attribute__((ext_vector_type(4)));

__device__ __forceinline__ void accum4(f4_t xv, f4_t tv, float ncf,
                                       float& s_inter, float& s_match, float& s_sig) {
#pragma unroll
    for (int j = 0; j < 4; ++j) {
        float tt = tv[j];
        float z  = 0.5f - fabsf(xv[j] - tt);
        float sg = __builtin_amdgcn_rcpf(1.0f + __expf(-z));
        float m  = (tt == floorf(tt) && tt >= 0.f && tt <= ncf) ? 1.f : 0.f;
        s_sig   += sg;
        s_match += m;
        s_inter += sg * m;
    }
}

__global__ __launch_bounds__(BLOCK) void soft_iou_partial(
    const float* __restrict__ x,
    const float* __restrict__ t,
    const int* __restrict__ ncls_p,
    float* __restrict__ pI,     // [gridDim.x]
    float* __restrict__ pM,     // [gridDim.x]
    float* __restrict__ pS,     // [gridDim.x]
    int n)
{
    const int tid = threadIdx.x;
    const long long nthreads = (long long)gridDim.x * BLOCK;
    const long long gtid     = (long long)blockIdx.x * BLOCK + tid;

    const float ncf = (float)(*ncls_p);

    float s_inter = 0.f, s_match = 0.f, s_sig = 0.f;

    const long long nvec = (long long)n >> 2;   // float4 count
    const f4_t* __restrict__ x4 = (const f4_t*)x;
    const f4_t* __restrict__ t4 = (const f4_t*)t;

    long long i = gtid;
    // straight-line round: 2*PAIRS independent NT dwordx4 loads, interleaved
    // x/t so accum-k only waits on the two oldest outstanding loads.
    for (; i + (PAIRS - 1) * nthreads < nvec; i += (long long)PAIRS * nthreads) {
        f4_t xv[PAIRS], tv[PAIRS];
#pragma unroll
        for (int k = 0; k < PAIRS; ++k) {
            xv[k] = __builtin_nontemporal_load(&x4[i + (long long)k * nthreads]);
            tv[k] = __builtin_nontemporal_load(&t4[i + (long long)k * nthreads]);
        }
        __builtin_amdgcn_sched_barrier(0);
#pragma unroll
        for (int k = 0; k < PAIRS; ++k)
            accum4(xv[k], tv[k], ncf, s_inter, s_match, s_sig);
    }
    // remaining full float4s
    for (; i < nvec; i += nthreads) {
        accum4(x4[i], t4[i], ncf, s_inter, s_match, s_sig);
    }
    // scalar tail (n % 4)
    for (long long k = (nvec << 2) + gtid; k < n; k += nthreads) {
        float tt = t[k];
        float z  = 0.5f - fabsf(x[k] - tt);
        float sg = __builtin_amdgcn_rcpf(1.0f + __expf(-z));
        float m  = (tt == floorf(tt) && tt >= 0.f && tt <= ncf) ? 1.f : 0.f;
        s_sig += sg; s_match += m; s_inter += sg * m;
    }

    // wave (64-lane) reduction
#pragma unroll
    for (int off = 32; off > 0; off >>= 1) {
        s_inter += __shfl_down(s_inter, off, 64);
        s_match += __shfl_down(s_match, off, 64);
        s_sig   += __shfl_down(s_sig,   off, 64);
    }

    __shared__ float sh[3][4];   // 4 waves for block=256
    const int wid = tid >> 6;
    const int lid = tid & 63;
    if (lid == 0) { sh[0][wid] = s_inter; sh[1][wid] = s_match; sh[2][wid] = s_sig; }
    __syncthreads();

    if (tid == 0) {
        pI[blockIdx.x] = sh[0][0] + sh[0][1] + sh[0][2] + sh[0][3];
        pM[blockIdx.x] = sh[1][0] + sh[1][1] + sh[1][2] + sh[1][3];
        pS[blockIdx.x] = sh[2][0] + sh[2][1] + sh[2][2] + sh[2][3];
    }
}

__global__ __launch_bounds__(256) void soft_iou_final(
    const float* __restrict__ pI,
    const float* __restrict__ pM,
    const float* __restrict__ pS,
    const int* __restrict__ ncls_p,
    float* __restrict__ out,
    int g)      // g multiple of 4 (grid is a multiple of 4 blocks)
{
    const int tid = threadIdx.x;
    const f4_t* pI4 = (const f4_t*)pI;
    const f4_t* pM4 = (const f4_t*)pM;
    const f4_t* pS4 = (const f4_t*)pS;
    const int g4 = g >> 2;
    float si = 0.f, sm = 0.f, ss = 0.f;
    for (int i = tid; i < g4; i += 256) {
        f4_t a = pI4[i], b = pM4[i], c = pS4[i];
        si += a[0] + a[1] + a[2] + a[3];
        sm += b[0] + b[1] + b[2] + b[3];
        ss += c[0] + c[1] + c[2] + c[3];
    }
    // tail if g not multiple of 4
    for (int i = (g4 << 2) + tid; i < g; i += 256) {
        si += pI[i]; sm += pM[i]; ss += pS[i];
    }
#pragma unroll
    for (int off = 32; off > 0; off >>= 1) {
        si += __shfl_down(si, off, 64);
        sm += __shfl_down(sm, off, 64);
        ss += __shfl_down(ss, off, 64);
    }
    __shared__ float sh[3][4];
    const int wid = tid >> 6;
    const int lid = tid & 63;
    if (lid == 0) { sh[0][wid] = si; sh[1][wid] = sm; sh[2][wid] = ss; }
    __syncthreads();
    if (tid == 0) {
        float I = sh[0][0] + sh[0][1] + sh[0][2] + sh[0][3];
        float M = sh[1][0] + sh[1][1] + sh[1][2] + sh[1][3];
        float S = sh[2][0] + sh[2][1] + sh[2][2] + sh[2][3];
        float ncf = (float)(*ncls_p);
        float uni = M + (ncf + 1.f) * S - I;
        out[0] = 1.f - (I + 1.f) / (uni + 1.f);
    }
}

extern "C" void kernel_launch(void* const* d_in, const int* in_sizes, int n_in,
                              void* d_out, int out_size, void* d_ws, size_t ws_size,
                              hipStream_t stream) {
    const float* x  = (const float*)d_in[0];
    const float* t  = (const float*)d_in[1];
    const int*   nc = (const int*)d_in[2];
    float* out = (float*)d_out;
    const int n = in_sizes[0];

    // grid sized so most threads do exactly one straight-line round
    long long nvec = (long long)n >> 2;
    long long threads_needed = (nvec + PAIRS - 1) / PAIRS;
    int grid = (int)((threads_needed + BLOCK - 1) / BLOCK);
    if (grid < 1) grid = 1;
    if (grid > MAXGRID) grid = MAXGRID;

    float* pI = (float*)d_ws;
    float* pM = pI + MAXGRID;
    float* pS = pM + MAXGRID;

    soft_iou_partial<<<grid, BLOCK, 0, stream>>>(x, t, nc, pI, pM, pS, n);
    soft_iou_final<<<1, 256, 0, stream>>>(pI, pM, pS, nc, out, grid);
}